// Round 4
// baseline (1225.194 us; speedup 1.0000x reference)
//
#include <hip/hip_runtime.h>
#include <hip/hip_bf16.h>
#include <cstdint>

#define H 128
#define VV 100
#define CC 1000
#define ER_N 250
#define NODE_IN_N 82
#define EDGE_IN_N 6
#define MROWS 112   // 7 m-tiles of 16 (100 rows padded)
#define LDA 136     // bf16 row stride (+8 pad breaks pow2 -> 2-way frag reads, free)

typedef short short8 __attribute__((ext_vector_type(8)));
typedef float floatx4 __attribute__((ext_vector_type(4)));
typedef __hip_bfloat16 bf16;

// ---------------- weight prep: fp32 [Ksrc x 128] -> bf16 B-fragment order ----------
// dst[((kc*8+nt)*64+lane)*8 + j] = W[kc*32+(lane>>4)*8+j][nt*16+(lane&15)]
__global__ __launch_bounds__(256) void prep_wfrag(const float* __restrict__ W,
                                                  bf16* __restrict__ dst,
                                                  int Ksrc, int total) {
  int idx = blockIdx.x * 256 + threadIdx.x;
  if (idx >= total) return;
  int j = idx & 7, lane = (idx >> 3) & 63, nt = (idx >> 9) & 7, kc = idx >> 12;
  int k = kc * 32 + (lane >> 4) * 8 + j;
  int n = nt * 16 + (lane & 15);
  float v = (k < Ksrc) ? W[(size_t)k * H + n] : 0.f;
  dst[idx] = __float2bfloat16(v);
}

// ---------------- MFMA accumulate: acc += A(LDS,112xLDA) @ Wf(global frags) --------
// wave owns n-tiles {2w, 2w+1}; A-frag A[m=l16][k=quad*8+j]; C row=quad*4+r, col=l16.
template<int CHUNKS>
__device__ __forceinline__ void gemm_acc(floatx4 acc[7][2], const bf16* A,
                                         const bf16* __restrict__ Wf,
                                         int lane, int wave, int quad, int l16) {
#pragma unroll
  for (int kc = 0; kc < CHUNKS; ++kc) {
    short8 b0 = *(const short8*)(Wf + ((size_t)((kc * 8 + wave * 2 + 0) * 64 + lane)) * 8);
    short8 b1 = *(const short8*)(Wf + ((size_t)((kc * 8 + wave * 2 + 1) * 64 + lane)) * 8);
#pragma unroll
    for (int m = 0; m < 7; ++m) {
      short8 a = *(const short8*)(A + (m * 16 + l16) * LDA + kc * 32 + quad * 8);
      acc[m][0] = __builtin_amdgcn_mfma_f32_16x16x32_bf16(a, b0, acc[m][0], 0, 0, 0);
      acc[m][1] = __builtin_amdgcn_mfma_f32_16x16x32_bf16(a, b1, acc[m][1], 0, 0, 0);
    }
  }
}

__device__ __forceinline__ void epilogue(floatx4 acc[7][2], const float* __restrict__ bias,
                                         bool relu, bf16* Out,
                                         int wave, int quad, int l16) {
#pragma unroll
  for (int nn = 0; nn < 2; ++nn) {
    int col = (wave * 2 + nn) * 16 + l16;
    float bb = bias[col];
#pragma unroll
    for (int m = 0; m < 7; ++m)
#pragma unroll
      for (int r = 0; r < 4; ++r) {
        float v = acc[m][nn][r] + bb;
        if (relu) v = fmaxf(v, 0.f);
        Out[(m * 16 + quad * 4 + r) * LDA + col] = __float2bfloat16(v);
      }
  }
}

__device__ __forceinline__ void zero_acc(floatx4 acc[7][2]) {
#pragma unroll
  for (int m = 0; m < 7; ++m) {
    acc[m][0] = (floatx4){0.f, 0.f, 0.f, 0.f};
    acc[m][1] = (floatx4){0.f, 0.f, 0.f, 0.f};
  }
}

// one WLN layer, fully in LDS. sH: h in/out. sT/sAgg scratch.
__device__ __forceinline__ void wln_layer(
    bf16* sH, bf16* sT, float* sAgg, const float* sEf, float* sWb,
    const int* sEdge,
    const bf16* __restrict__ wf_msg, const float* __restrict__ bmsg,
    const float* __restrict__ WmBot,
    const bf16* __restrict__ wf_new, const float* __restrict__ bnew,
    int tid, int lane, int wave, int quad, int l16) {
  // stage edge-part weights (read 2 barriers later)
  for (int f = tid; f < EDGE_IN_N * H; f += 256) sWb[f] = WmBot[f];
  // msg GEMM: t = h @ Wm_top + bm   (no relu)
  floatx4 acc[7][2];
  zero_acc(acc);
  gemm_acc<4>(acc, sH, wf_msg, lane, wave, quad, l16);
  // zero agg (not read until after barrier)
  for (int f = tid; f < VV * H / 4; f += 256)
    ((float4*)sAgg)[f] = make_float4(0.f, 0.f, 0.f, 0.f);
  epilogue(acc, bmsg, false, sT, wave, quad, l16);
  __syncthreads();

  // edge pass: wave handles one edge per iteration, lane covers cols {2l, 2l+1}
  float wb[EDGE_IN_N][2];
#pragma unroll
  for (int k = 0; k < EDGE_IN_N; ++k) {
    float2 w2 = *(const float2*)&sWb[k * H + 2 * lane];
    wb[k][0] = w2.x;
    wb[k][1] = w2.y;
  }
  for (int it = 0; it < (ER_N + 3) / 4; ++it) {
    int e = it * 4 + wave;
    if (e < ER_N) {
      int pk = sEdge[e];
      int s = pk >> 16, d = pk & 0xffff;
      uint32_t tt = *(const uint32_t*)&sT[s * LDA + 2 * lane];
      float u0 = __uint_as_float((tt & 0xffffu) << 16);
      float u1 = __uint_as_float((tt >> 16) << 16);
      float4 ea = *(const float4*)&sEf[e * 8];
      float2 eb = *(const float2*)&sEf[e * 8 + 4];
      u0 = fmaf(ea.x, wb[0][0], u0); u1 = fmaf(ea.x, wb[0][1], u1);
      u0 = fmaf(ea.y, wb[1][0], u0); u1 = fmaf(ea.y, wb[1][1], u1);
      u0 = fmaf(ea.z, wb[2][0], u0); u1 = fmaf(ea.z, wb[2][1], u1);
      u0 = fmaf(ea.w, wb[3][0], u0); u1 = fmaf(ea.w, wb[3][1], u1);
      u0 = fmaf(eb.x, wb[4][0], u0); u1 = fmaf(eb.x, wb[4][1], u1);
      u0 = fmaf(eb.y, wb[5][0], u0); u1 = fmaf(eb.y, wb[5][1], u1);
      u0 = fmaxf(u0, 0.f);
      u1 = fmaxf(u1, 0.f);
      atomicAdd(&sAgg[d * H + 2 * lane], u0);
      atomicAdd(&sAgg[d * H + 2 * lane + 1], u1);
    }
  }
  __syncthreads();

  // convert agg fp32 -> bf16 into sT (t is dead now)
  for (int f = tid; f < VV * H / 2; f += 256) {
    int r = f >> 6, cc = (f & 63) << 1;
    float2 v = *(const float2*)&sAgg[r * H + cc];
    __hip_bfloat162 p;
    p.x = __float2bfloat16(v.x);
    p.y = __float2bfloat16(v.y);
    *(__hip_bfloat162*)&sT[r * LDA + cc] = p;
  }
  __syncthreads();

  // update GEMM: h = relu(h @ Wn_top + agg @ Wn_bot + bn)
  zero_acc(acc);
  gemm_acc<4>(acc, sH, wf_new, lane, wave, quad, l16);
  gemm_acc<4>(acc, sT, wf_new + 4 * 4096, lane, wave, quad, l16);
  __syncthreads();  // all reads of sH complete before overwrite
  epilogue(acc, bnew, true, sH, wave, quad, l16);
  __syncthreads();
}

template<bool PRODUCT>
__global__ __launch_bounds__(256) void wln_fused(
    const float* __restrict__ X, const float* __restrict__ EF,
    const int* __restrict__ SRC, const int* __restrict__ DST,
    const bf16* __restrict__ wf_proj, const float* __restrict__ bproj,
    const bf16* __restrict__ wf_msg, const float* __restrict__ bmsg,
    const float* __restrict__ WmBot,
    const bf16* __restrict__ wf_new, const float* __restrict__ bnew,
    const bf16* __restrict__ wf_msgd, const float* __restrict__ bmsgd,
    const float* __restrict__ WmdBot,
    const bf16* __restrict__ wf_newd, const float* __restrict__ bnewd,
    bf16* __restrict__ hr_global,
    const float* __restrict__ W1, const float* __restrict__ b1,
    const float* __restrict__ W2, const float* __restrict__ b2,
    const float* __restrict__ scores, float* __restrict__ out) {
  __shared__ bf16 sH[MROWS * LDA];
  __shared__ bf16 sT[MROWS * LDA];
  __shared__ float sAgg[VV * H];
  __shared__ float sEf[ER_N * 8];
  __shared__ float sWb[EDGE_IN_N * H];
  __shared__ int sEdge[ER_N];
  __shared__ float sRed[256];
  __shared__ float sG[H];

  const int tid = threadIdx.x;
  const int lane = tid & 63, wave = tid >> 6;
  const int quad = lane >> 4, l16 = lane & 15;
  const int c = blockIdx.x;
  const int no = c * VV;
  const long eo = (long)c * ER_N;

  // ---- stage edges (local ids packed), edge feats, X -> sT (KPAD=96) ----
  for (int e = tid; e < ER_N; e += 256) {
    int s = SRC[eo + e] - no;
    int d = DST[eo + e] - no;
    sEdge[e] = (s << 16) | d;
  }
  for (int f = tid; f < ER_N * EDGE_IN_N; f += 256) {
    int e = f / EDGE_IN_N, k = f - e * EDGE_IN_N;
    sEf[e * 8 + k] = EF[(eo + e) * EDGE_IN_N + k];
  }
  for (int f = tid; f < MROWS * 96; f += 256) {
    int r = f / 96, cc = f - r * 96;
    float v = (r < VV && cc < NODE_IN_N) ? X[(size_t)(no + r) * NODE_IN_N + cc] : 0.f;
    sT[r * LDA + cc] = __float2bfloat16(v);
  }
  __syncthreads();

  // ---- input projection: h = relu(X @ Wproj + bproj) ----
  {
    floatx4 acc[7][2];
    zero_acc(acc);
    gemm_acc<3>(acc, sT, wf_proj, lane, wave, quad, l16);
    epilogue(acc, bproj, true, sH, wave, quad, l16);
  }
  __syncthreads();

  // ---- 3 shared-weight encoder layers ----
  for (int l = 0; l < 3; ++l)
    wln_layer(sH, sT, sAgg, sEf, sWb, sEdge, wf_msg, bmsg, WmBot, wf_new, bnew,
              tid, lane, wave, quad, l16);

  if (!PRODUCT) {
    for (int f = tid; f < VV * H; f += 256)
      hr_global[f] = sH[(f >> 7) * LDA + (f & 127)];
    return;
  }

  // ---- diff against broadcast reactant ----
  for (int f = tid; f < VV * H; f += 256) {
    int r = f >> 7, j = f & 127;
    float v = __bfloat162float(sH[r * LDA + j]) - __bfloat162float(hr_global[f]);
    sH[r * LDA + j] = __float2bfloat16(v);
  }
  __syncthreads();

  // ---- diff WLN layer ----
  wln_layer(sH, sT, sAgg, sEf, sWb, sEdge, wf_msgd, bmsgd, WmdBot, wf_newd, bnewd,
            tid, lane, wave, quad, l16);

  // ---- head: sum-pool + MLP + candidate score ----
  {
    int j = tid & 127, half = tid >> 7;
    float p = 0.f;
    for (int v = half * 50; v < (half + 1) * 50; ++v)
      p += __bfloat162float(sH[v * LDA + j]);
    sRed[tid] = p;
  }
  __syncthreads();
  if (tid < H) sG[tid] = sRed[tid] + sRed[tid + 128];
  __syncthreads();
  {
    int j = tid & 127, half = tid >> 7;
    float a = 0.f;
    for (int k = half * 64; k < (half + 1) * 64; ++k)
      a = fmaf(sG[k], W1[(size_t)k * H + j], a);
    sRed[tid] = a;
  }
  __syncthreads();
  if (tid < H) {
    float m = sRed[tid] + sRed[tid + 128] + b1[tid];
    sG[tid] = fmaxf(m, 0.f) * W2[tid];
  }
  __syncthreads();
  for (int s = 64; s > 0; s >>= 1) {
    if (tid < s) sG[tid] += sG[tid + s];
    __syncthreads();
  }
  if (tid == 0) out[c] = sG[0] + b2[0] + scores[c];
}

extern "C" void kernel_launch(void* const* d_in, const int* in_sizes, int n_in,
                              void* d_out, int out_size, void* d_ws, size_t ws_size,
                              hipStream_t stream) {
  const float* Xr  = (const float*)d_in[0];
  const float* Ere = (const float*)d_in[1];
  const float* Xp  = (const float*)d_in[2];
  const float* Epe = (const float*)d_in[3];
  const float* sc  = (const float*)d_in[4];
  const float* Wp  = (const float*)d_in[5];
  const float* bp  = (const float*)d_in[6];
  const float* Wm  = (const float*)d_in[7];
  const float* bm  = (const float*)d_in[8];
  const float* Wn  = (const float*)d_in[9];
  const float* bn  = (const float*)d_in[10];
  const float* Wmd = (const float*)d_in[11];
  const float* bmd = (const float*)d_in[12];
  const float* Wnd = (const float*)d_in[13];
  const float* bnd = (const float*)d_in[14];
  const float* W1  = (const float*)d_in[15];
  const float* b1  = (const float*)d_in[16];
  const float* W2  = (const float*)d_in[17];
  const float* b2  = (const float*)d_in[18];
  const int* rsrc  = (const int*)d_in[19];
  const int* rdst  = (const int*)d_in[20];
  const int* psrc  = (const int*)d_in[21];
  const int* pdst  = (const int*)d_in[22];

  bf16* wf_proj = (bf16*)d_ws;            // 3*4096
  bf16* wf_msg  = wf_proj + 3 * 4096;     // 4*4096
  bf16* wf_new  = wf_msg + 4 * 4096;      // 8*4096
  bf16* wf_msgd = wf_new + 8 * 4096;      // 4*4096
  bf16* wf_newd = wf_msgd + 4 * 4096;     // 8*4096
  bf16* hr      = wf_newd + 8 * 4096;     // VV*H

  float* out = (float*)d_out;

  // ---- weight prep (B-frag bf16) ----
  prep_wfrag<<<(3 * 4096 + 255) / 256, 256, 0, stream>>>(Wp, wf_proj, NODE_IN_N, 3 * 4096);
  prep_wfrag<<<(4 * 4096 + 255) / 256, 256, 0, stream>>>(Wm, wf_msg, H, 4 * 4096);
  prep_wfrag<<<(8 * 4096 + 255) / 256, 256, 0, stream>>>(Wn, wf_new, 2 * H, 8 * 4096);
  prep_wfrag<<<(4 * 4096 + 255) / 256, 256, 0, stream>>>(Wmd, wf_msgd, H, 4 * 4096);
  prep_wfrag<<<(8 * 4096 + 255) / 256, 256, 0, stream>>>(Wnd, wf_newd, 2 * H, 8 * 4096);

  // ---- reactant (1 block) then products (1000 blocks) ----
  wln_fused<false><<<1, 256, 0, stream>>>(
      Xr, Ere, rsrc, rdst, wf_proj, bp, wf_msg, bm, Wm + H * H, wf_new, bn,
      wf_msgd, bmd, Wmd + H * H, wf_newd, bnd, hr, W1, b1, W2, b2, sc, out);
  wln_fused<true><<<CC, 256, 0, stream>>>(
      Xp, Epe, psrc, pdst, wf_proj, bp, wf_msg, bm, Wm + H * H, wf_new, bn,
      wf_msgd, bmd, Wmd + H * H, wf_newd, bnd, hr, W1, b1, W2, b2, sc, out);
}

// Round 5
// 450.809 us; speedup vs baseline: 2.7178x; 2.7178x over previous
//
#include <hip/hip_runtime.h>
#include <hip/hip_bf16.h>
#include <cstdint>

#define H 128
#define VV 100
#define CC 1000
#define ER_N 250
#define NODE_IN_N 82
#define EDGE_IN_N 6
#define MROWS 112   // 7 m-tiles of 16
#define LDA 136     // bf16 row stride (+8 pad)
#define NT 512      // threads per block (8 waves)

typedef short short8 __attribute__((ext_vector_type(8)));
typedef float floatx4 __attribute__((ext_vector_type(4)));
typedef __hip_bfloat16 bf16;

// ---------------- weight prep: fp32 [Ksrc x 128] -> bf16 B-fragment order ----------
// dst[((kc*8+nt)*64+lane)*8 + j] = W[kc*32+(lane>>4)*8+j][nt*16+(lane&15)]
__global__ __launch_bounds__(256) void prep_wfrag(const float* __restrict__ W,
                                                  bf16* __restrict__ dst,
                                                  int Ksrc, int total) {
  int idx = blockIdx.x * 256 + threadIdx.x;
  if (idx >= total) return;
  int j = idx & 7, lane = (idx >> 3) & 63, nt = (idx >> 9) & 7, kc = idx >> 12;
  int k = kc * 32 + (lane >> 4) * 8 + j;
  int n = nt * 16 + (lane & 15);
  float v = (k < Ksrc) ? W[(size_t)k * H + n] : 0.f;
  dst[idx] = __float2bfloat16(v);
}

// ---------------- MFMA accumulate over 8 waves: wave = (mh<<2)|g --------------------
// g: n-tiles {2g,2g+1}; mh: m-tiles [mh*4 .. mh*4+mc), mc = mh?3:4.
template<int CHUNKS>
__device__ __forceinline__ void gemm_acc(floatx4 acc[4][2], const bf16* A,
                                         const bf16* __restrict__ Wf,
                                         int lane, int g, int m0, int mc,
                                         int quad, int l16) {
#pragma unroll
  for (int kc = 0; kc < CHUNKS; ++kc) {
    short8 b0 = *(const short8*)(Wf + ((size_t)((kc * 8 + 2 * g + 0) * 64 + lane)) * 8);
    short8 b1 = *(const short8*)(Wf + ((size_t)((kc * 8 + 2 * g + 1) * 64 + lane)) * 8);
#pragma unroll
    for (int mi = 0; mi < 4; ++mi)
      if (mi < mc) {
        short8 a = *(const short8*)(A + ((m0 + mi) * 16 + l16) * LDA + kc * 32 + quad * 8);
        acc[mi][0] = __builtin_amdgcn_mfma_f32_16x16x32_bf16(a, b0, acc[mi][0], 0, 0, 0);
        acc[mi][1] = __builtin_amdgcn_mfma_f32_16x16x32_bf16(a, b1, acc[mi][1], 0, 0, 0);
      }
  }
}

__device__ __forceinline__ void epilogue(floatx4 acc[4][2], const float* __restrict__ bias,
                                         bool relu, bf16* Out,
                                         int g, int m0, int mc, int quad, int l16) {
#pragma unroll
  for (int nn = 0; nn < 2; ++nn) {
    int col = (2 * g + nn) * 16 + l16;
    float bb = bias[col];
#pragma unroll
    for (int mi = 0; mi < 4; ++mi)
      if (mi < mc)
#pragma unroll
        for (int r = 0; r < 4; ++r) {
          float v = acc[mi][nn][r] + bb;
          if (relu) v = fmaxf(v, 0.f);
          Out[((m0 + mi) * 16 + quad * 4 + r) * LDA + col] = __float2bfloat16(v);
        }
  }
}

__device__ __forceinline__ void zero_acc(floatx4 acc[4][2]) {
#pragma unroll
  for (int mi = 0; mi < 4; ++mi) {
    acc[mi][0] = (floatx4){0.f, 0.f, 0.f, 0.f};
    acc[mi][1] = (floatx4){0.f, 0.f, 0.f, 0.f};
  }
}

// one WLN layer fully in LDS; gather-CSR edge pass, no atomics.
__device__ __forceinline__ void wln_layer(
    bf16* sH, bf16* sT, const float* sEf, const int* sRowPtr, const int* sEidx,
    const bf16* __restrict__ wf_msg, const float* __restrict__ bmsg,
    const float* __restrict__ WmBot,
    const bf16* __restrict__ wf_new, const float* __restrict__ bnew,
    int tid, int lane, int g, int m0, int mc, int quad, int l16,
    int q8, int c2) {
  floatx4 acc[4][2];
  // msg GEMM: t = h @ Wm_top + bm
  zero_acc(acc);
  gemm_acc<4>(acc, sH, wf_msg, lane, g, m0, mc, quad, l16);
  epilogue(acc, bmsg, false, sT, g, m0, mc, quad, l16);
  __syncthreads();

  // gather pass: thread (node q8+8i, cols {2c2,2c2+1}), agg in registers
  float wb[EDGE_IN_N][2];
#pragma unroll
  for (int k = 0; k < EDGE_IN_N; ++k) {
    wb[k][0] = WmBot[k * H + 2 * c2];
    wb[k][1] = WmBot[k * H + 2 * c2 + 1];
  }
  float f0[13], f1[13];
#pragma unroll
  for (int i = 0; i < 13; ++i) {
    f0[i] = 0.f;
    f1[i] = 0.f;
    int n = q8 + 8 * i;
    if (n < VV) {
      int p0 = sRowPtr[n], p1 = sRowPtr[n + 1];
      for (int p = p0; p < p1; ++p) {
        int v = sEidx[p];
        int s = v & 127, e = v >> 7;
        uint32_t tt = *(const uint32_t*)&sT[s * LDA + 2 * c2];
        float u0 = __uint_as_float((tt & 0xffffu) << 16);
        float u1 = __uint_as_float((tt >> 16) << 16);
        const float* ep = &sEf[e * EDGE_IN_N];
#pragma unroll
        for (int k = 0; k < EDGE_IN_N; ++k) {
          float ev = ep[k];
          u0 = fmaf(ev, wb[k][0], u0);
          u1 = fmaf(ev, wb[k][1], u1);
        }
        f0[i] += fmaxf(u0, 0.f);
        f1[i] += fmaxf(u1, 0.f);
      }
    }
  }
  __syncthreads();  // all sT reads complete
#pragma unroll
  for (int i = 0; i < 13; ++i) {
    int n = q8 + 8 * i;
    if (n < VV) {
      __hip_bfloat162 p;
      p.x = __float2bfloat16(f0[i]);
      p.y = __float2bfloat16(f1[i]);
      *(__hip_bfloat162*)&sT[n * LDA + 2 * c2] = p;
    }
  }
  __syncthreads();  // agg visible

  // update GEMM: h = relu(h @ Wn_top + agg @ Wn_bot + bn)
  zero_acc(acc);
  gemm_acc<4>(acc, sH, wf_new, lane, g, m0, mc, quad, l16);
  gemm_acc<4>(acc, sT, wf_new + 4 * 4096, lane, g, m0, mc, quad, l16);
  __syncthreads();  // sH reads done before overwrite
  epilogue(acc, bnew, true, sH, g, m0, mc, quad, l16);
  __syncthreads();
}

template<bool PRODUCT>
__global__ __launch_bounds__(NT, 4) void wln_fused(
    const float* __restrict__ X, const float* __restrict__ EF,
    const int* __restrict__ SRC, const int* __restrict__ DST,
    const bf16* __restrict__ wf_proj, const float* __restrict__ bproj,
    const bf16* __restrict__ wf_msg, const float* __restrict__ bmsg,
    const float* __restrict__ WmBot,
    const bf16* __restrict__ wf_new, const float* __restrict__ bnew,
    const bf16* __restrict__ wf_msgd, const float* __restrict__ bmsgd,
    const float* __restrict__ WmdBot,
    const bf16* __restrict__ wf_newd, const float* __restrict__ bnewd,
    bf16* __restrict__ hr_global,
    const float* __restrict__ W1, const float* __restrict__ b1,
    const float* __restrict__ W2, const float* __restrict__ b2,
    const float* __restrict__ scores, float* __restrict__ out) {
  __shared__ bf16 sH[MROWS * LDA];      // 30464 B
  __shared__ bf16 sT[MROWS * LDA];      // 30464 B
  __shared__ float sEf[ER_N * EDGE_IN_N];  // 6000 B
  __shared__ int sRowPtr[VV + 1];
  __shared__ int sCnt[VV];              // doubles as cursor
  __shared__ int sScan[128];
  __shared__ int sSD[ER_N];
  __shared__ int sEidx[ER_N];
  __shared__ float sRed[NT];            // 2048 B
  __shared__ float sG[H];

  const int tid = threadIdx.x;
  const int lane = tid & 63;
  const int wave = tid >> 6;
  const int quad = (lane >> 4) & 3, l16 = lane & 15;
  const int g = wave & 3, mh = wave >> 2;
  const int m0 = mh * 4, mc = mh ? 3 : 4;
  const int q8 = tid >> 6, c2 = tid & 63;
  const int c = blockIdx.x;
  const int no = c * VV;
  const long eo = (long)c * ER_N;

  // ---- stage: edges, CSR build, edge feats, X -> sT ----
  if (tid < VV) sCnt[tid] = 0;
  __syncthreads();
  if (tid < ER_N) {
    int s = SRC[eo + tid] - no;
    int d = DST[eo + tid] - no;
    sSD[tid] = (d << 16) | s;
    atomicAdd(&sCnt[d], 1);
  }
  for (int f = tid; f < ER_N * EDGE_IN_N; f += NT)
    sEf[f] = EF[eo * EDGE_IN_N + f];
  for (int f = tid; f < MROWS * 96; f += NT) {
    int r = f / 96, cc = f - r * 96;
    float v = (r < VV && cc < NODE_IN_N) ? X[(size_t)(no + r) * NODE_IN_N + cc] : 0.f;
    sT[r * LDA + cc] = __float2bfloat16(v);
  }
  __syncthreads();
  int myc = 0;
  if (tid < 128) {
    myc = (tid < VV) ? sCnt[tid] : 0;
    sScan[tid] = myc;
  }
  __syncthreads();
  for (int off = 1; off < 128; off <<= 1) {
    int x = (tid < 128 && tid >= off) ? sScan[tid - off] : 0;
    __syncthreads();
    if (tid < 128) sScan[tid] += x;
    __syncthreads();
  }
  if (tid < VV) {
    int ex = sScan[tid] - myc;
    sRowPtr[tid] = ex;
    sCnt[tid] = ex;  // cursor
  }
  if (tid == 0) sRowPtr[VV] = ER_N;
  __syncthreads();
  if (tid < ER_N) {
    int sd = sSD[tid];
    int p = atomicAdd(&sCnt[sd >> 16], 1);
    sEidx[p] = (sd & 0xffff) | (tid << 7);
  }
  __syncthreads();

  // ---- input projection: h = relu(X @ Wproj + bproj), KPAD=96 ----
  {
    floatx4 acc[4][2];
    zero_acc(acc);
    gemm_acc<3>(acc, sT, wf_proj, lane, g, m0, mc, quad, l16);
    epilogue(acc, bproj, true, sH, g, m0, mc, quad, l16);
  }
  __syncthreads();

  // ---- 3 shared-weight encoder layers ----
  for (int l = 0; l < 3; ++l)
    wln_layer(sH, sT, sEf, sRowPtr, sEidx, wf_msg, bmsg, WmBot, wf_new, bnew,
              tid, lane, g, m0, mc, quad, l16, q8, c2);

  if (!PRODUCT) {
    for (int f = tid; f < VV * H; f += NT)
      hr_global[f] = sH[(f >> 7) * LDA + (f & 127)];
    return;
  }

  // ---- diff against broadcast reactant ----
  for (int f = tid; f < VV * H; f += NT) {
    int r = f >> 7, j = f & 127;
    float v = __bfloat162float(sH[r * LDA + j]) - __bfloat162float(hr_global[f]);
    sH[r * LDA + j] = __float2bfloat16(v);
  }
  __syncthreads();

  // ---- diff WLN layer ----
  wln_layer(sH, sT, sEf, sRowPtr, sEidx, wf_msgd, bmsgd, WmdBot, wf_newd, bnewd,
            tid, lane, g, m0, mc, quad, l16, q8, c2);

  // ---- head: sum-pool + MLP + candidate score ----
  {
    int j = tid & 127, qq = tid >> 7;  // 4 row-groups of 25
    float p = 0.f;
    for (int v = qq * 25; v < qq * 25 + 25; ++v)
      p += __bfloat162float(sH[v * LDA + j]);
    sRed[tid] = p;
  }
  __syncthreads();
  if (tid < H)
    sG[tid] = sRed[tid] + sRed[tid + 128] + sRed[tid + 256] + sRed[tid + 384];
  __syncthreads();
  {
    int j = tid & 127, qq = tid >> 7;
    float a = 0.f;
    for (int k = qq * 32; k < qq * 32 + 32; ++k)
      a = fmaf(sG[k], W1[(size_t)k * H + j], a);
    sRed[tid] = a;
  }
  __syncthreads();
  if (tid < H) {
    float m = sRed[tid] + sRed[tid + 128] + sRed[tid + 256] + sRed[tid + 384] + b1[tid];
    sG[tid] = fmaxf(m, 0.f) * W2[tid];
  }
  __syncthreads();
  for (int s2 = 64; s2 > 0; s2 >>= 1) {
    if (tid < s2) sG[tid] += sG[tid + s2];
    __syncthreads();
  }
  if (tid == 0) out[c] = sG[0] + b2[0] + scores[c];
}

extern "C" void kernel_launch(void* const* d_in, const int* in_sizes, int n_in,
                              void* d_out, int out_size, void* d_ws, size_t ws_size,
                              hipStream_t stream) {
  const float* Xr  = (const float*)d_in[0];
  const float* Ere = (const float*)d_in[1];
  const float* Xp  = (const float*)d_in[2];
  const float* Epe = (const float*)d_in[3];
  const float* sc  = (const float*)d_in[4];
  const float* Wp  = (const float*)d_in[5];
  const float* bp  = (const float*)d_in[6];
  const float* Wm  = (const float*)d_in[7];
  const float* bm  = (const float*)d_in[8];
  const float* Wn  = (const float*)d_in[9];
  const float* bn  = (const float*)d_in[10];
  const float* Wmd = (const float*)d_in[11];
  const float* bmd = (const float*)d_in[12];
  const float* Wnd = (const float*)d_in[13];
  const float* bnd = (const float*)d_in[14];
  const float* W1  = (const float*)d_in[15];
  const float* b1  = (const float*)d_in[16];
  const float* W2  = (const float*)d_in[17];
  const float* b2  = (const float*)d_in[18];
  const int* rsrc  = (const int*)d_in[19];
  const int* rdst  = (const int*)d_in[20];
  const int* psrc  = (const int*)d_in[21];
  const int* pdst  = (const int*)d_in[22];

  bf16* wf_proj = (bf16*)d_ws;            // 3*4096
  bf16* wf_msg  = wf_proj + 3 * 4096;     // 4*4096
  bf16* wf_new  = wf_msg + 4 * 4096;      // 8*4096
  bf16* wf_msgd = wf_new + 8 * 4096;      // 4*4096
  bf16* wf_newd = wf_msgd + 4 * 4096;     // 8*4096
  bf16* hr      = wf_newd + 8 * 4096;     // VV*H

  float* out = (float*)d_out;

  // ---- weight prep (B-frag bf16) ----
  prep_wfrag<<<(3 * 4096 + 255) / 256, 256, 0, stream>>>(Wp, wf_proj, NODE_IN_N, 3 * 4096);
  prep_wfrag<<<(4 * 4096 + 255) / 256, 256, 0, stream>>>(Wm, wf_msg, H, 4 * 4096);
  prep_wfrag<<<(8 * 4096 + 255) / 256, 256, 0, stream>>>(Wn, wf_new, 2 * H, 8 * 4096);
  prep_wfrag<<<(4 * 4096 + 255) / 256, 256, 0, stream>>>(Wmd, wf_msgd, H, 4 * 4096);
  prep_wfrag<<<(8 * 4096 + 255) / 256, 256, 0, stream>>>(Wnd, wf_newd, 2 * H, 8 * 4096);

  // ---- reactant (1 block) then products (1000 blocks) ----
  wln_fused<false><<<1, NT, 0, stream>>>(
      Xr, Ere, rsrc, rdst, wf_proj, bp, wf_msg, bm, Wm + H * H, wf_new, bn,
      wf_msgd, bmd, Wmd + H * H, wf_newd, bnd, hr, W1, b1, W2, b2, sc, out);
  wln_fused<true><<<CC, NT, 0, stream>>>(
      Xp, Epe, psrc, pdst, wf_proj, bp, wf_msg, bm, Wm + H * H, wf_new, bn,
      wf_msgd, bmd, Wmd + H * H, wf_newd, bnd, hr, W1, b1, W2, b2, sc, out);
}

// Round 6
// 450.248 us; speedup vs baseline: 2.7212x; 1.0012x over previous
//
#include <hip/hip_runtime.h>
#include <hip/hip_bf16.h>
#include <cstdint>

#define H 128
#define VV 100
#define CC 1000
#define ER_N 250
#define NODE_IN_N 82
#define EDGE_IN_N 6
#define MROWS 112   // 7 m-tiles of 16
#define LDA 136     // bf16 row stride: 272B rows keep b128 16B-aligned; 2-way banks (free)
#define NT 1024     // 16 waves per block, 1 block/CU

typedef short short8 __attribute__((ext_vector_type(8)));
typedef float floatx4 __attribute__((ext_vector_type(4)));
typedef __hip_bfloat16 bf16;

// ---------------- merged weight prep: all 5 matrices -> bf16 B-frag order, one launch
// dst[((kc*8+nt)*64+lane)*8 + j] = W[kc*32+(lane>>4)*8+j][nt*16+(lane&15)] per segment
__global__ __launch_bounds__(256) void prep_wfrag_all(
    const float* __restrict__ Wp, const float* __restrict__ Wm,
    const float* __restrict__ Wn, const float* __restrict__ Wmd,
    const float* __restrict__ Wnd, bf16* __restrict__ dst) {
  int idx = blockIdx.x * 256 + threadIdx.x;
  if (idx >= 27 * 4096) return;
  const float* W;
  int Ksrc, local = idx;
  if (idx < 3 * 4096)       { W = Wp;  Ksrc = NODE_IN_N; }
  else if (idx < 7 * 4096)  { W = Wm;  Ksrc = H;     local -= 3 * 4096; }
  else if (idx < 15 * 4096) { W = Wn;  Ksrc = 2 * H; local -= 7 * 4096; }
  else if (idx < 19 * 4096) { W = Wmd; Ksrc = H;     local -= 15 * 4096; }
  else                      { W = Wnd; Ksrc = 2 * H; local -= 19 * 4096; }
  int j = local & 7, lane = (local >> 3) & 63, nt = (local >> 9) & 7, kc = local >> 12;
  int k = kc * 32 + ((lane >> 4) & 3) * 8 + j;
  int n = nt * 16 + (lane & 15);
  float v = (k < Ksrc) ? W[(size_t)k * H + n] : 0.f;
  dst[idx] = __float2bfloat16(v);
}

// ---------------- MFMA accumulate over 16 waves: wave = (mg<<2)|g ------------------
// g: n-tiles {2g,2g+1}; mg: m-tiles {2mg, 2mg+1} (mg=3 -> only tile 6).
template<int CHUNKS>
__device__ __forceinline__ void gemm_acc(floatx4 acc[2][2], const bf16* A,
                                         const bf16* __restrict__ Wf,
                                         int lane, int g, int m0, int mc,
                                         int quad, int l16) {
#pragma unroll
  for (int kc = 0; kc < CHUNKS; ++kc) {
    short8 b0 = *(const short8*)(Wf + ((size_t)((kc * 8 + 2 * g + 0) * 64 + lane)) * 8);
    short8 b1 = *(const short8*)(Wf + ((size_t)((kc * 8 + 2 * g + 1) * 64 + lane)) * 8);
#pragma unroll
    for (int mi = 0; mi < 2; ++mi)
      if (mi < mc) {
        short8 a = *(const short8*)(A + ((m0 + mi) * 16 + l16) * LDA + kc * 32 + quad * 8);
        acc[mi][0] = __builtin_amdgcn_mfma_f32_16x16x32_bf16(a, b0, acc[mi][0], 0, 0, 0);
        acc[mi][1] = __builtin_amdgcn_mfma_f32_16x16x32_bf16(a, b1, acc[mi][1], 0, 0, 0);
      }
  }
}

__device__ __forceinline__ void epilogue(floatx4 acc[2][2], const float* __restrict__ bias,
                                         bool relu, bf16* Out,
                                         int g, int m0, int mc, int quad, int l16) {
#pragma unroll
  for (int nn = 0; nn < 2; ++nn) {
    int col = (2 * g + nn) * 16 + l16;
    float bb = bias[col];
#pragma unroll
    for (int mi = 0; mi < 2; ++mi)
      if (mi < mc)
#pragma unroll
        for (int r = 0; r < 4; ++r) {
          float v = acc[mi][nn][r] + bb;
          if (relu) v = fmaxf(v, 0.f);
          Out[((m0 + mi) * 16 + quad * 4 + r) * LDA + col] = __float2bfloat16(v);
        }
  }
}

__device__ __forceinline__ void zero_acc(floatx4 acc[2][2]) {
#pragma unroll
  for (int mi = 0; mi < 2; ++mi) {
    acc[mi][0] = (floatx4){0.f, 0.f, 0.f, 0.f};
    acc[mi][1] = (floatx4){0.f, 0.f, 0.f, 0.f};
  }
}

// gather: thread (node q16+16i, col-pair c2) writes agg DIRECTLY to sAgg (no reg arrays)
__device__ __forceinline__ void gather(const bf16* sT, bf16* sAgg, const float* sEf,
                                       const int* sRowPtr, const int* sEidx,
                                       const float* __restrict__ WmBot,
                                       int q16, int c2) {
  float wb[EDGE_IN_N][2];
#pragma unroll
  for (int k = 0; k < EDGE_IN_N; ++k) {
    float2 w2 = *(const float2*)&WmBot[k * H + 2 * c2];
    wb[k][0] = w2.x;
    wb[k][1] = w2.y;
  }
#pragma unroll
  for (int i = 0; i < 7; ++i) {
    int n = q16 + 16 * i;
    if (n < VV) {
      int p0 = sRowPtr[n], p1 = sRowPtr[n + 1];
      float a0 = 0.f, a1 = 0.f;
      for (int p = p0; p < p1; ++p) {
        int v = sEidx[p];
        int s = v & 127, e = v >> 7;
        uint32_t tt = *(const uint32_t*)&sT[s * LDA + 2 * c2];
        float u0 = __uint_as_float((tt & 0xffffu) << 16);
        float u1 = __uint_as_float((tt >> 16) << 16);
        float4 ea = *(const float4*)&sEf[e * 8];
        float2 eb = *(const float2*)&sEf[e * 8 + 4];
        u0 = fmaf(ea.x, wb[0][0], u0); u1 = fmaf(ea.x, wb[0][1], u1);
        u0 = fmaf(ea.y, wb[1][0], u0); u1 = fmaf(ea.y, wb[1][1], u1);
        u0 = fmaf(ea.z, wb[2][0], u0); u1 = fmaf(ea.z, wb[2][1], u1);
        u0 = fmaf(ea.w, wb[3][0], u0); u1 = fmaf(ea.w, wb[3][1], u1);
        u0 = fmaf(eb.x, wb[4][0], u0); u1 = fmaf(eb.x, wb[4][1], u1);
        u0 = fmaf(eb.y, wb[5][0], u0); u1 = fmaf(eb.y, wb[5][1], u1);
        a0 += fmaxf(u0, 0.f);
        a1 += fmaxf(u1, 0.f);
      }
      __hip_bfloat162 pk;
      pk.x = __float2bfloat16(a0);
      pk.y = __float2bfloat16(a1);
      *(__hip_bfloat162*)&sAgg[n * LDA + 2 * c2] = pk;  // does not alias sT: no buffering
    }
  }
}

// one WLN layer: 3 barriers. update's h-part overlaps the gather (sH stable).
__device__ __forceinline__ void wln_layer(
    bf16* sH, bf16* sT, bf16* sAgg, const float* sEf,
    const int* sRowPtr, const int* sEidx,
    const bf16* __restrict__ wf_msg, const float* __restrict__ bmsg,
    const float* __restrict__ WmBot,
    const bf16* __restrict__ wf_new, const float* __restrict__ bnew,
    int lane, int g, int m0, int mc, int quad, int l16, int q16, int c2) {
  floatx4 accM[2][2];
  zero_acc(accM);
  gemm_acc<4>(accM, sH, wf_msg, lane, g, m0, mc, quad, l16);
  epilogue(accM, bmsg, false, sT, g, m0, mc, quad, l16);
  __syncthreads();  // bar A: t visible

  floatx4 accU[2][2];
  zero_acc(accU);
  gemm_acc<4>(accU, sH, wf_new, lane, g, m0, mc, quad, l16);  // h-part, sH stable
  gather(sT, sAgg, sEf, sRowPtr, sEidx, WmBot, q16, c2);
  __syncthreads();  // bar B: sAgg visible; all sH/sT reads complete

  gemm_acc<4>(accU, sAgg, wf_new + 4 * 4096, lane, g, m0, mc, quad, l16);
  epilogue(accU, bnew, true, sH, g, m0, mc, quad, l16);  // safe: sH readers done at bar B
  __syncthreads();  // bar C: new h visible
}

template<bool PRODUCT>
__global__ __launch_bounds__(NT, 4) void wln_fused(
    const float* __restrict__ X, const float* __restrict__ EF,
    const int* __restrict__ SRC, const int* __restrict__ DST,
    const bf16* __restrict__ wf_proj, const float* __restrict__ bproj,
    const bf16* __restrict__ wf_msg, const float* __restrict__ bmsg,
    const float* __restrict__ WmBot,
    const bf16* __restrict__ wf_new, const float* __restrict__ bnew,
    const bf16* __restrict__ wf_msgd, const float* __restrict__ bmsgd,
    const float* __restrict__ WmdBot,
    const bf16* __restrict__ wf_newd, const float* __restrict__ bnewd,
    bf16* __restrict__ hr_global,
    const float* __restrict__ W1, const float* __restrict__ b1,
    const float* __restrict__ W2, const float* __restrict__ b2,
    const float* __restrict__ scores, float* __restrict__ out) {
  __shared__ bf16 sH[MROWS * LDA];         // 30464 B
  __shared__ bf16 sT[MROWS * LDA];         // 30464 B
  __shared__ bf16 sAgg[MROWS * LDA];       // 30464 B (dedicated: kills reg buffering)
  __shared__ float sEf[ER_N * 8];          // 8000 B (padded for float4)
  __shared__ int sRowPtr[VV + 1];
  __shared__ int sCnt[VV];
  __shared__ int sScan[128];
  __shared__ int sSD[ER_N];
  __shared__ int sEidx[ER_N];
  __shared__ float sRed[NT];               // 4096 B
  __shared__ float sG[H];

  const int tid = threadIdx.x;
  const int lane = tid & 63;
  const int wave = tid >> 6;               // 0..15
  const int quad = (lane >> 4) & 3, l16 = lane & 15;
  const int g = wave & 3, mg = wave >> 2;
  const int m0 = mg * 2, mc = (mg < 3) ? 2 : 1;
  const int q16 = tid >> 6, c2 = tid & 63;
  const int c = blockIdx.x;
  const int no = c * VV;
  const long eo = (long)c * ER_N;

  // ---- stage edges + CSR build + edge feats + X -> sT ----
  if (tid < VV) sCnt[tid] = 0;
  __syncthreads();
  if (tid < ER_N) {
    int s = SRC[eo + tid] - no;
    int d = DST[eo + tid] - no;
    sSD[tid] = (d << 16) | s;
    atomicAdd(&sCnt[d], 1);
  }
  for (int f = tid; f < ER_N * EDGE_IN_N; f += NT) {
    int e = f / EDGE_IN_N, k = f - e * EDGE_IN_N;
    sEf[e * 8 + k] = EF[eo * EDGE_IN_N + f];
  }
  for (int f = tid; f < MROWS * 96; f += NT) {
    int r = f / 96, cc = f - r * 96;
    float v = (r < VV && cc < NODE_IN_N) ? X[(size_t)(no + r) * NODE_IN_N + cc] : 0.f;
    sT[r * LDA + cc] = __float2bfloat16(v);
  }
  __syncthreads();
  int myc = 0;
  if (tid < 128) {
    myc = (tid < VV) ? sCnt[tid] : 0;
    sScan[tid] = myc;
  }
  __syncthreads();
  for (int off = 1; off < 128; off <<= 1) {
    int x = (tid < 128 && tid >= off) ? sScan[tid - off] : 0;
    __syncthreads();
    if (tid < 128) sScan[tid] += x;
    __syncthreads();
  }
  if (tid < VV) {
    int ex = sScan[tid] - myc;
    sRowPtr[tid] = ex;
    sCnt[tid] = ex;  // cursor
  }
  if (tid == 0) sRowPtr[VV] = ER_N;
  __syncthreads();
  if (tid < ER_N) {
    int sd = sSD[tid];
    int p = atomicAdd(&sCnt[sd >> 16], 1);
    sEidx[p] = (sd & 0xffff) | (tid << 7);
  }
  __syncthreads();

  // ---- input projection: h = relu(X @ Wproj + bproj), KPAD=96 ----
  {
    floatx4 acc[2][2];
    zero_acc(acc);
    gemm_acc<3>(acc, sT, wf_proj, lane, g, m0, mc, quad, l16);
    epilogue(acc, bproj, true, sH, g, m0, mc, quad, l16);
  }
  __syncthreads();

  // ---- 3 shared-weight encoder layers ----
  for (int l = 0; l < 3; ++l)
    wln_layer(sH, sT, sAgg, sEf, sRowPtr, sEidx, wf_msg, bmsg, WmBot, wf_new, bnew,
              lane, g, m0, mc, quad, l16, q16, c2);

  if (!PRODUCT) {
    for (int f = tid; f < VV * H; f += NT)
      hr_global[f] = sH[(f >> 7) * LDA + (f & 127)];
    return;
  }

  // ---- diff against broadcast reactant ----
  for (int f = tid; f < VV * H; f += NT) {
    int r = f >> 7, j = f & 127;
    float v = __bfloat162float(sH[r * LDA + j]) - __bfloat162float(hr_global[f]);
    sH[r * LDA + j] = __float2bfloat16(v);
  }
  __syncthreads();

  // ---- diff WLN layer ----
  wln_layer(sH, sT, sAgg, sEf, sRowPtr, sEidx, wf_msgd, bmsgd, WmdBot, wf_newd, bnewd,
            lane, g, m0, mc, quad, l16, q16, c2);

  // ---- head: sum-pool + MLP + candidate score ----
  {
    int j = tid & 127, qq = tid >> 7;  // 8 row-groups: {13,13,13,13,12,12,12,12}
    int start = qq * 12 + ((qq < 4) ? qq : 4);
    int cnt = (qq < 4) ? 13 : 12;
    float p = 0.f;
    for (int v = start; v < start + cnt; ++v)
      p += __bfloat162float(sH[v * LDA + j]);
    sRed[tid] = p;
  }
  __syncthreads();
  if (tid < H) {
    float s = 0.f;
#pragma unroll
    for (int q = 0; q < 8; ++q) s += sRed[q * 128 + tid];
    sG[tid] = s;
  }
  __syncthreads();
  {
    int j = tid & 127, qq = tid >> 7;
    float a = 0.f;
    for (int k = qq * 16; k < qq * 16 + 16; ++k)
      a = fmaf(sG[k], W1[(size_t)k * H + j], a);
    sRed[tid] = a;
  }
  __syncthreads();
  if (tid < H) {
    float m = b1[tid];
#pragma unroll
    for (int q = 0; q < 8; ++q) m += sRed[q * 128 + tid];
    sG[tid] = fmaxf(m, 0.f) * W2[tid];
  }
  __syncthreads();
  for (int s2 = 64; s2 > 0; s2 >>= 1) {
    if (tid < s2) sG[tid] += sG[tid + s2];
    __syncthreads();
  }
  if (tid == 0) out[c] = sG[0] + b2[0] + scores[c];
}

extern "C" void kernel_launch(void* const* d_in, const int* in_sizes, int n_in,
                              void* d_out, int out_size, void* d_ws, size_t ws_size,
                              hipStream_t stream) {
  const float* Xr  = (const float*)d_in[0];
  const float* Ere = (const float*)d_in[1];
  const float* Xp  = (const float*)d_in[2];
  const float* Epe = (const float*)d_in[3];
  const float* sc  = (const float*)d_in[4];
  const float* Wp  = (const float*)d_in[5];
  const float* bp  = (const float*)d_in[6];
  const float* Wm  = (const float*)d_in[7];
  const float* bm  = (const float*)d_in[8];
  const float* Wn  = (const float*)d_in[9];
  const float* bn  = (const float*)d_in[10];
  const float* Wmd = (const float*)d_in[11];
  const float* bmd = (const float*)d_in[12];
  const float* Wnd = (const float*)d_in[13];
  const float* bnd = (const float*)d_in[14];
  const float* W1  = (const float*)d_in[15];
  const float* b1  = (const float*)d_in[16];
  const float* W2  = (const float*)d_in[17];
  const float* b2  = (const float*)d_in[18];
  const int* rsrc  = (const int*)d_in[19];
  const int* rdst  = (const int*)d_in[20];
  const int* psrc  = (const int*)d_in[21];
  const int* pdst  = (const int*)d_in[22];

  bf16* wf_proj = (bf16*)d_ws;            // 3*4096   (contiguous: prep order)
  bf16* wf_msg  = wf_proj + 3 * 4096;     // 4*4096
  bf16* wf_new  = wf_msg + 4 * 4096;      // 8*4096
  bf16* wf_msgd = wf_new + 8 * 4096;      // 4*4096
  bf16* wf_newd = wf_msgd + 4 * 4096;     // 8*4096
  bf16* hr      = wf_newd + 8 * 4096;     // VV*H

  float* out = (float*)d_out;

  // ---- single merged weight-prep launch ----
  prep_wfrag_all<<<(27 * 4096) / 256, 256, 0, stream>>>(Wp, Wm, Wn, Wmd, Wnd, wf_proj);

  // ---- reactant (1 block) then products (1000 blocks) ----
  wln_fused<false><<<1, NT, 0, stream>>>(
      Xr, Ere, rsrc, rdst, wf_proj, bp, wf_msg, bm, Wm + H * H, wf_new, bn,
      wf_msgd, bmd, Wmd + H * H, wf_newd, bnd, hr, W1, b1, W2, b2, sc, out);
  wln_fused<true><<<CC, NT, 0, stream>>>(
      Xp, Epe, psrc, pdst, wf_proj, bp, wf_msg, bm, Wm + H * H, wf_new, bn,
      wf_msgd, bmd, Wmd + H * H, wf_newd, bnd, hr, W1, b1, W2, b2, sc, out);
}